// Round 3
// baseline (263.707 us; speedup 1.0000x reference)
//
#include <hip/hip_runtime.h>
#include <math.h>
#include <stdint.h>

#define F_INN 128
#define HIDD 64
#define ALPHA 0.2f

typedef float v4f  __attribute__((ext_vector_type(4)));
typedef float v2f  __attribute__((ext_vector_type(2)));
typedef short s8v  __attribute__((ext_vector_type(8)));

__device__ __forceinline__ float wave_sum(float v) {
    #pragma unroll
    for (int m = 32; m >= 1; m >>= 1) v += __shfl_xor(v, m, 64);
    return v;
}
__device__ __forceinline__ int ctz64(unsigned long long x) { return (int)__builtin_ctzll(x); }
__device__ __forceinline__ int clz64(unsigned long long x) { return (int)__builtin_clzll(x); }
// fp32 -> bf16 (RNE) and back
__device__ __forceinline__ unsigned short f2bf(float f) {
    unsigned u = __float_as_uint(f);
    return (unsigned short)((u + 0x7FFFu + ((u >> 16) & 1u)) >> 16);
}
__device__ __forceinline__ float bf2f(unsigned short h) {
    return __uint_as_float(((unsigned)h) << 16);
}
// unpack 2 bf16 (packed in a uint) -> v2f  (2 VALU)
__device__ __forceinline__ v2f unpk(unsigned u) {
    const uint2 t = make_uint2(u << 16, u & 0xFFFF0000u);
    v2f r; r.x = __uint_as_float(t.x); r.y = __uint_as_float(t.y);
    return r;
}

// K0: block 0 -> w1=W@a1, w2=W@a2; blocks 1..32 -> pack W into MFMA B-frag
// layout (split hi/lo bf16). rptr is GONE — k3 is edge-centric now.
__global__ void k02_prep(const float* __restrict__ W, const float* __restrict__ a1,
                         const float* __restrict__ a2,
                         float* __restrict__ w1, float* __restrict__ w2,
                         unsigned short* __restrict__ whF, unsigned short* __restrict__ wlF)
{
    const int tid = threadIdx.x, b = blockIdx.x;
    if (b == 0) {
        if (tid < 128) {
            float s = 0.f;
            for (int h = 0; h < HIDD; ++h) s = fmaf(W[tid * HIDD + h], a1[h], s);
            w1[tid] = s;
        } else {
            const int f = tid - 128;
            float s = 0.f;
            for (int h = 0; h < HIDD; ++h) s = fmaf(W[f * HIDD + h], a2[h], s);
            w2[f] = s;
        }
        return;
    }
    const int g = (b - 1) * 256 + tid;   // 32*256 = 8192
    const int j = g & 7, lane = (g >> 3) & 63, kc = (g >> 9) & 3, nt = (g >> 11) & 3;
    const int k = kc * 32 + (lane >> 4) * 8 + j;
    const int nn = nt * 16 + (lane & 15);
    const float w = W[k * HIDD + nn];
    const unsigned short hi = f2bf(w);
    whF[g] = hi;
    wlF[g] = f2bf(w - bf2f(hi));
}

// K1: fts16 = bf16(seq @ W) via split-bf16 3-term MFMA (fp32-accurate);
// f1/f2 fused. One wave = 16 nodes, direct global A-frag loads.
// At its ~64 MB memory floor — do not touch.
__global__ __launch_bounds__(256) void k1_feat(
    const float* __restrict__ seq,
    const unsigned short* __restrict__ whF, const unsigned short* __restrict__ wlF,
    const float* __restrict__ w1, const float* __restrict__ w2,
    const float* __restrict__ b1, const float* __restrict__ b2,
    unsigned short* __restrict__ fts16, float* __restrict__ f1, float* __restrict__ f2,
    int n)
{
    const int lane = threadIdx.x & 63;
    const long wid = blockIdx.x * 4 + (threadIdx.x >> 6);
    const long n0 = wid * 16;
    if (n0 >= n) return;
    const int m = lane & 15, q = lane >> 4, fb = q * 8;
    long nd = n0 + m; if (nd >= n) nd = n - 1;
    const float* srow = seq + nd * F_INN;

    s8v Ah[4], Al[4];
    float p1 = 0.f, p2 = 0.f;
    #pragma unroll
    for (int kc = 0; kc < 4; ++kc) {
        const v4f r0  = *(const v4f*)(srow + kc * 32 + fb);
        const v4f r1  = *(const v4f*)(srow + kc * 32 + fb + 4);
        const v4f u1a = *(const v4f*)(w1 + kc * 32 + fb);
        const v4f u1b = *(const v4f*)(w1 + kc * 32 + fb + 4);
        const v4f u2a = *(const v4f*)(w2 + kc * 32 + fb);
        const v4f u2b = *(const v4f*)(w2 + kc * 32 + fb + 4);
        #pragma unroll
        for (int j = 0; j < 8; ++j) {
            const float x  = (j < 4) ? r0[j] : r1[j - 4];
            const float wa = (j < 4) ? u1a[j] : u1b[j - 4];
            const float wb = (j < 4) ? u2a[j] : u2b[j - 4];
            const unsigned short h = f2bf(x);
            Ah[kc][j] = (short)h;
            Al[kc][j] = (short)f2bf(x - bf2f(h));
            p1 = fmaf(x, wa, p1);
            p2 = fmaf(x, wb, p2);
        }
    }

    v4f acc[4];
    #pragma unroll
    for (int nt = 0; nt < 4; ++nt) acc[nt] = (v4f){0.f, 0.f, 0.f, 0.f};
    #pragma unroll
    for (int nt = 0; nt < 4; ++nt) {
        #pragma unroll
        for (int kc = 0; kc < 4; ++kc) {
            const int fo = ((nt * 4 + kc) * 64 + lane) * 8;
            const s8v Bh = *(const s8v*)(whF + fo);
            const s8v Bl = *(const s8v*)(wlF + fo);
            acc[nt] = __builtin_amdgcn_mfma_f32_16x16x32_bf16(Ah[kc], Bh, acc[nt], 0, 0, 0);
            acc[nt] = __builtin_amdgcn_mfma_f32_16x16x32_bf16(Ah[kc], Bl, acc[nt], 0, 0, 0);
            acc[nt] = __builtin_amdgcn_mfma_f32_16x16x32_bf16(Al[kc], Bh, acc[nt], 0, 0, 0);
        }
    }

    // C layout: col = lane&15, row = (lane>>4)*4 + reg
    #pragma unroll
    for (int nt = 0; nt < 4; ++nt) {
        #pragma unroll
        for (int reg = 0; reg < 4; ++reg) {
            const long node = n0 + q * 4 + reg;
            if (node < n) fts16[node * HIDD + nt * 16 + m] = f2bf(acc[nt][reg]);
        }
    }
    p1 += __shfl_xor(p1, 16, 64); p1 += __shfl_xor(p1, 32, 64);
    p2 += __shfl_xor(p2, 16, 64); p2 += __shfl_xor(p2, 32, 64);
    if (lane < 16 && n0 + lane < n) {
        f1[n0 + lane] = p1 + b1[0];
        f2[n0 + lane] = p2 + b2[0];
    }
}

// K3 v3 (edge-centric): wave w OWNS all rows whose first edge lies in
// [64w, 64w+64). It loads 128 edges (its window + lookahead) coalesced,
// derives row boundaries from erow in-register (ballots — no rptr table),
// issues ALL owned gathers + f1/f2 reads in one batch, then consumes per
// owned row with position masks. Chain: RT1(streams) -> RT2(gathers) per
// ~2 rows, vs 3 RTs per row before. All 64 lanes always carry live edges.
// Empty rows: zero-stored by the owning window. Rows spanning >128 edges:
// streaming fallback (never hit at deg~Poisson(32), correctness only).
__global__ __launch_bounds__(256) void k3_attn(
    const int* __restrict__ erow, const int* __restrict__ ecol,
    const float* __restrict__ evals, const float* __restrict__ f1,
    const float* __restrict__ f2, const uint4* __restrict__ fts4,
    float* __restrict__ out, int n, int E)
{
    __shared__ int   stc[4][128];
    __shared__ float stz[4][128];
    __shared__ float red[4][8][64];
    const int lane = threadIdx.x & 63;
    const int wv   = threadIdx.x >> 6;
    const long w   = (long)blockIdx.x * 4 + wv;
    const long e0  = w * 64;
    if (e0 >= E) return;
    const int sub = lane >> 3, hc = lane & 7;

    // ---- RT1: coalesced edge streams (window + lookahead) + rprev ----
    const long eA = e0 + lane, eB = e0 + 64 + lane;
    int rA = n, cA = 0; float evA = 0.f;
    if (eA < E) { rA = erow[eA]; cA = ecol[eA]; evA = evals[eA]; }
    int rB = n, cB = 0; float evB = 0.f;
    if (eB < E) { rB = erow[eB]; cB = ecol[eB]; evB = evals[eB]; }
    const int rprev = (w > 0) ? erow[e0 - 1] : -1;

    // stage gather offsets (uint4 index of row start)
    stc[wv][lane]      = cA * 8;
    stc[wv][lane + 64] = cB * 8;

    // ---- RT2 (issued asap, all independent): f-table gathers ----
    const float f2A = f2[cA];
    const float f2B = f2[cB];
    const float f1A = f1[min(rA, n - 1)];
    const float f1B = f1[min(rB, n - 1)];

    // ---- ownership from erow (VALU/DS only, overlaps RT2) ----
    const long t0 = E - 1 - e0;
    const int lastL0 = (t0 < 63) ? (int)t0 : 63;
    const int rmax = __shfl(rA, lastL0, 64);
    const unsigned long long gt0 = __ballot(rA > rprev);
    const int gBase = gt0 ? ctz64(gt0) : 64;
    const unsigned long long bEnd = __ballot(rB > rmax);
    int gEnd = bEnd ? 64 + ctz64(bEnd) : 128;
    const bool needCont = (bEnd == 0ULL);
    if (rmax <= rprev) gEnd = gBase;          // window inside a continuing row
    const int nslots = (gEnd - gBase + 7) >> 3;

    // ---- issue ALL owned-row gathers (up to 16 in flight) ----
    uint4 u[16];
    #pragma unroll
    for (int p = 0; p < 16; ++p) {
        if (p < nslots) {
            int loc = gBase + p * 8 + sub;
            loc = (loc < gEnd) ? loc : (gEnd - 1);   // clamp tail (masked later)
            u[p] = fts4[stc[wv][loc] + hc];
        }
    }
    __builtin_amdgcn_sched_barrier(0);

    // ---- z per edge (waits f1/f2 only; gathers stay in flight) ----
    float lA = evA * (f1A + f2A); lA = (lA > 0.f) ? lA : ALPHA * lA;
    const float zA = (eA < E) ? __expf(lA) : 0.f;
    float lB = evB * (f1B + f2B); lB = (lB > 0.f) ? lB : ALPHA * lB;
    const float zB = (eB < E) ? __expf(lB) : 0.f;
    stz[wv][lane]      = zA;
    stz[wv][lane + 64] = zB;

    // ---- consume per owned row ----
    float* rd = &red[wv][0][0];
    for (int R = rprev + 1; R <= rmax; ++R) {
        const unsigned long long b0 = __ballot(rA == R);
        const unsigned long long b1 = __ballot(rB == R);
        if (!(b0 | b1)) {                              // empty row
            out[(size_t)R * HIDD + lane] = 0.f;
            continue;
        }
        const int sR = b0 ? ctz64(b0) : 64 + ctz64(b1);        // local, inclusive
        const int eR = b1 ? 128 - clz64(b1) : 64 - clz64(b0);  // local, exclusive

        v2f acc[4];
        #pragma unroll
        for (int t = 0; t < 4; ++t) { acc[t].x = 0.f; acc[t].y = 0.f; }

        const int pA = (sR - gBase) >> 3;
        const int pB = (eR - 1 - gBase) >> 3;
        #pragma unroll
        for (int p = 0; p < 16; ++p) {
            if (p >= pA && p <= pB) {
                const int loc = gBase + p * 8 + sub;
                float zz = stz[wv][(loc < 128) ? loc : 127];
                zz = (loc >= sR && loc < eR) ? zz : 0.f;
                v2f z2; z2.x = zz; z2.y = zz;
                acc[0] = __builtin_elementwise_fma(z2, unpk(u[p].x), acc[0]);
                acc[1] = __builtin_elementwise_fma(z2, unpk(u[p].y), acc[1]);
                acc[2] = __builtin_elementwise_fma(z2, unpk(u[p].z), acc[2]);
                acc[3] = __builtin_elementwise_fma(z2, unpk(u[p].w), acc[3]);
            }
        }
        float zm = ((lane >= sR && lane < eR) ? zA : 0.f)
                 + ((lane + 64 >= sR && lane + 64 < eR) ? zB : 0.f);

        // streaming fallback: row rmax extends past the 128 loaded edges
        if (R == rmax && needCont) {
            for (long base = e0 + 128; base < E; base += 64) {
                const long e = base + lane;
                int r2 = n, c2 = 0; float ev2 = 0.f;
                if (e < E) { r2 = erow[e]; c2 = ecol[e]; ev2 = evals[e]; }
                const float f2v = f2[c2];
                stc[wv][lane] = c2 * 8;               // stc/stz reuse safe: last row
                float l2 = ev2 * (f1[min(r2, n - 1)] + f2v);
                l2 = (l2 > 0.f) ? l2 : ALPHA * l2;
                const float z2s = (r2 == R) ? __expf(l2) : 0.f;
                stz[wv][lane] = z2s;
                zm += z2s;
                const unsigned long long bc = __ballot(r2 == R);  // prefix of lanes
                const int cnt = bc ? (64 - clz64(bc)) : 0;
                const int ns2 = (cnt + 7) >> 3;
                for (int p = 0; p < ns2; ++p) {
                    int loc = p * 8 + sub;
                    loc = (loc < cnt) ? loc : (cnt - 1);
                    const uint4 uu = fts4[stc[wv][loc] + hc];
                    float zz = stz[wv][loc];
                    zz = ((p * 8 + sub) < cnt) ? zz : 0.f;
                    v2f z2; z2.x = zz; z2.y = zz;
                    acc[0] = __builtin_elementwise_fma(z2, unpk(uu.x), acc[0]);
                    acc[1] = __builtin_elementwise_fma(z2, unpk(uu.y), acc[1]);
                    acc[2] = __builtin_elementwise_fma(z2, unpk(uu.z), acc[2]);
                    acc[3] = __builtin_elementwise_fma(z2, unpk(uu.w), acc[3]);
                }
                if (cnt < 64) break;
            }
        }

        const float s = wave_sum(zm);                  // z>0 always -> s>0
        // epilogue: LDS transpose, 8-way sum per feature, ELU, coalesced store
        *(v4f*)(rd + sub * 64 + hc * 8)     = (v4f){acc[0].x, acc[0].y, acc[1].x, acc[1].y};
        *(v4f*)(rd + sub * 64 + hc * 8 + 4) = (v4f){acc[2].x, acc[2].y, acc[3].x, acc[3].y};
        const float inv = __builtin_amdgcn_rcpf(s);
        float t = 0.f;
        #pragma unroll
        for (int q = 0; q < 8; ++q) t += rd[q * 64 + lane];
        float v = t * inv;
        v = (v > 0.f) ? v : (__expf(v) - 1.f);
        out[(size_t)R * HIDD + lane] = v;
    }

    // the wave holding the last edge zeroes any trailing empty rows
    if (e0 + 64 >= E) {
        for (int R = rmax + 1; R < n; ++R) out[(size_t)R * HIDD + lane] = 0.f;
    }
}

extern "C" void kernel_launch(void* const* d_in, const int* in_sizes, int n_in,
                              void* d_out, int out_size, void* d_ws, size_t ws_size,
                              hipStream_t stream)
{
    const float* seq   = (const float*)d_in[0];
    const int*   erow  = (const int*)  d_in[1];
    const int*   ecol  = (const int*)  d_in[2];
    const float* evals = (const float*)d_in[3];
    const float* W     = (const float*)d_in[4];
    const float* a1    = (const float*)d_in[5];
    const float* b1    = (const float*)d_in[6];
    const float* a2    = (const float*)d_in[7];
    const float* b2    = (const float*)d_in[8];
    // d_in[9] = bias_zero (zeros) — additive no-op, skipped.

    const int N = in_sizes[0] / F_INN;
    const int E = in_sizes[1];

    // workspace: fts16 | f1 | f2 | w1 | w2 | whF | wlF  (~14 MB)
    char* p = (char*)d_ws;
    unsigned short* fts16 = (unsigned short*)p; p += (size_t)N * HIDD * 2;
    float* f1 = (float*)p; p += (size_t)N * 4;
    float* f2 = (float*)p; p += (size_t)N * 4;
    p = (char*)(((uintptr_t)p + 15) & ~(uintptr_t)15);
    float* w1 = (float*)p; p += 128 * 4;
    float* w2 = (float*)p; p += 128 * 4;
    unsigned short* whF = (unsigned short*)p; p += 8192 * 2;
    unsigned short* wlF = (unsigned short*)p;

    float* out = (float*)d_out;

    k02_prep<<<33, 256, 0, stream>>>(W, a1, a2, w1, w2, whF, wlF);

    const int waves1  = (N + 15) / 16;
    const int blocks1 = (waves1 + 3) / 4;
    k1_feat<<<blocks1, 256, 0, stream>>>(seq, whF, wlF, w1, w2, b1, b2,
                                         fts16, f1, f2, N);

    const int waves3  = (E + 63) / 64;
    const int blocks3 = (waves3 + 3) / 4;
    k3_attn<<<blocks3, 256, 0, stream>>>(erow, ecol, evals, f1, f2,
                                         (const uint4*)fts16, out, N, E);
}

// Round 4
// 224.139 us; speedup vs baseline: 1.1765x; 1.1765x over previous
//
#include <hip/hip_runtime.h>
#include <math.h>
#include <stdint.h>

#define F_INN 128
#define HIDD 64
#define ALPHA 0.2f

typedef float v4f  __attribute__((ext_vector_type(4)));
typedef float v2f  __attribute__((ext_vector_type(2)));
typedef short s8v  __attribute__((ext_vector_type(8)));

__device__ __forceinline__ float wave_sum(float v) {
    #pragma unroll
    for (int m = 32; m >= 1; m >>= 1) v += __shfl_xor(v, m, 64);
    return v;
}
// fp32 -> bf16 (RNE) and back
__device__ __forceinline__ unsigned short f2bf(float f) {
    unsigned u = __float_as_uint(f);
    return (unsigned short)((u + 0x7FFFu + ((u >> 16) & 1u)) >> 16);
}
__device__ __forceinline__ float bf2f(unsigned short h) {
    return __uint_as_float(((unsigned)h) << 16);
}
// unpack 2 bf16 (packed in a uint) -> v2f  (2 VALU)
__device__ __forceinline__ v2f unpk(unsigned u) {
    const uint2 t = make_uint2(u << 16, u & 0xFFFF0000u);
    v2f r; r.x = __uint_as_float(t.x); r.y = __uint_as_float(t.y);
    return r;
}

// K0: block 0 -> w1=W@a1, w2=W@a2; blocks 1..32 -> pack W into MFMA B-frag
// layout (split hi/lo bf16).
__global__ void k0_prep(const float* __restrict__ W, const float* __restrict__ a1,
                        const float* __restrict__ a2,
                        float* __restrict__ w1, float* __restrict__ w2,
                        unsigned short* __restrict__ whF, unsigned short* __restrict__ wlF)
{
    const int tid = threadIdx.x, b = blockIdx.x;
    if (b == 0) {
        if (tid < 128) {
            float s = 0.f;
            for (int h = 0; h < HIDD; ++h) s = fmaf(W[tid * HIDD + h], a1[h], s);
            w1[tid] = s;
        } else {
            const int f = tid - 128;
            float s = 0.f;
            for (int h = 0; h < HIDD; ++h) s = fmaf(W[f * HIDD + h], a2[h], s);
            w2[f] = s;
        }
        return;
    }
    const int g = (b - 1) * 256 + tid;   // 32*256 = 8192
    const int j = g & 7, lane = (g >> 3) & 63, kc = (g >> 9) & 3, nt = (g >> 11) & 3;
    const int k = kc * 32 + (lane >> 4) * 8 + j;
    const int nn = nt * 16 + (lane & 15);
    const float w = W[k * HIDD + nn];
    const unsigned short hi = f2bf(w);
    whF[g] = hi;
    wlF[g] = f2bf(w - bf2f(hi));
}

// K1: fts16 = bf16(seq @ W) via split-bf16 3-term MFMA (fp32-accurate);
// f1/f2 fused. One wave = 16 nodes, direct global A-frag loads.
// At its ~64 MB memory floor — do not touch.
__global__ __launch_bounds__(256) void k1_feat(
    const float* __restrict__ seq,
    const unsigned short* __restrict__ whF, const unsigned short* __restrict__ wlF,
    const float* __restrict__ w1, const float* __restrict__ w2,
    const float* __restrict__ b1, const float* __restrict__ b2,
    unsigned short* __restrict__ fts16, float* __restrict__ f1, float* __restrict__ f2,
    int n)
{
    const int lane = threadIdx.x & 63;
    const long wid = blockIdx.x * 4 + (threadIdx.x >> 6);
    const long n0 = wid * 16;
    if (n0 >= n) return;
    const int m = lane & 15, q = lane >> 4, fb = q * 8;
    long nd = n0 + m; if (nd >= n) nd = n - 1;
    const float* srow = seq + nd * F_INN;

    s8v Ah[4], Al[4];
    float p1 = 0.f, p2 = 0.f;
    #pragma unroll
    for (int kc = 0; kc < 4; ++kc) {
        const v4f r0  = *(const v4f*)(srow + kc * 32 + fb);
        const v4f r1  = *(const v4f*)(srow + kc * 32 + fb + 4);
        const v4f u1a = *(const v4f*)(w1 + kc * 32 + fb);
        const v4f u1b = *(const v4f*)(w1 + kc * 32 + fb + 4);
        const v4f u2a = *(const v4f*)(w2 + kc * 32 + fb);
        const v4f u2b = *(const v4f*)(w2 + kc * 32 + fb + 4);
        #pragma unroll
        for (int j = 0; j < 8; ++j) {
            const float x  = (j < 4) ? r0[j] : r1[j - 4];
            const float wa = (j < 4) ? u1a[j] : u1b[j - 4];
            const float wb = (j < 4) ? u2a[j] : u2b[j - 4];
            const unsigned short h = f2bf(x);
            Ah[kc][j] = (short)h;
            Al[kc][j] = (short)f2bf(x - bf2f(h));
            p1 = fmaf(x, wa, p1);
            p2 = fmaf(x, wb, p2);
        }
    }

    v4f acc[4];
    #pragma unroll
    for (int nt = 0; nt < 4; ++nt) acc[nt] = (v4f){0.f, 0.f, 0.f, 0.f};
    #pragma unroll
    for (int nt = 0; nt < 4; ++nt) {
        #pragma unroll
        for (int kc = 0; kc < 4; ++kc) {
            const int fo = ((nt * 4 + kc) * 64 + lane) * 8;
            const s8v Bh = *(const s8v*)(whF + fo);
            const s8v Bl = *(const s8v*)(wlF + fo);
            acc[nt] = __builtin_amdgcn_mfma_f32_16x16x32_bf16(Ah[kc], Bh, acc[nt], 0, 0, 0);
            acc[nt] = __builtin_amdgcn_mfma_f32_16x16x32_bf16(Ah[kc], Bl, acc[nt], 0, 0, 0);
            acc[nt] = __builtin_amdgcn_mfma_f32_16x16x32_bf16(Al[kc], Bh, acc[nt], 0, 0, 0);
        }
    }

    // C layout: col = lane&15, row = (lane>>4)*4 + reg
    #pragma unroll
    for (int nt = 0; nt < 4; ++nt) {
        #pragma unroll
        for (int reg = 0; reg < 4; ++reg) {
            const long node = n0 + q * 4 + reg;
            if (node < n) fts16[node * HIDD + nt * 16 + m] = f2bf(acc[nt][reg]);
        }
    }
    p1 += __shfl_xor(p1, 16, 64); p1 += __shfl_xor(p1, 32, 64);
    p2 += __shfl_xor(p2, 16, 64); p2 += __shfl_xor(p2, 32, 64);
    if (lane < 16 && n0 + lane < n) {
        f1[n0 + lane] = p1 + b1[0];
        f2[n0 + lane] = p2 + b2[0];
    }
}

// KZ (new): per-edge streaming pass. Computes zE[e] = exp(leaky(ev*(f1[r]+f2[c])))
// — pulling the ENTIRE softmax-numerator chain (the f2 gather + exp that sat on
// k3's critical path) into a coalesced, high-occupancy, latency-tolerant kernel.
// Also does the rptr boundary scatter (R2-proven; reads erow anyway), replacing
// the 22-probe dependent binary search entirely.
__global__ __launch_bounds__(256) void kz_edge(
    const int* __restrict__ erow, const int* __restrict__ ecol,
    const float* __restrict__ evals, const float* __restrict__ f1,
    const float* __restrict__ f2, float* __restrict__ zE,
    int* __restrict__ rptr, int n, int E)
{
    const long e = (long)blockIdx.x * 256 + threadIdx.x;
    if (e >= E) return;
    const int r = erow[e];
    const int c = ecol[e];
    const float ev = evals[e];
    float l = ev * (f1[r] + f2[c]);
    l = (l > 0.f) ? l : ALPHA * l;
    zE[e] = __expf(l);
    // rptr[rr] = first edge index with erow >= rr (erow sorted ascending)
    const int ra = (e == 0) ? -1 : erow[e - 1];
    for (int rr = ra + 1; rr <= r; ++rr) rptr[rr] = (int)e;
    if (e == E - 1) {
        for (int rr = r + 1; rr <= n; ++rr) rptr[rr] = E;
    }
}

// Batched gather (R0-proven skeleton, exp chain deleted): read (c,z) pairs from
// LDS stage, issue ALL 2*G row-gathers up-front, then consume. One edge per 8
// lanes (uint4 = 8 bf16 of the 128B row). Padded entries: z=0, row 0 (L1-hot).
template<int G>
__device__ __forceinline__ void gather_batch(
    const uint4* __restrict__ fts4, const int2* __restrict__ st,
    int sub, int hc, v2f* acc)
{
    uint4 u[2 * G];
    float zj[2 * G];
    #pragma unroll
    for (int p = 0; p < 2 * G; ++p) {
        const int2 cz = st[p * 8 + sub];
        zj[p] = __int_as_float(cz.y);
        u[p]  = fts4[cz.x + hc];
    }
    #pragma unroll
    for (int p = 0; p < 2 * G; ++p) {
        v2f z2; z2.x = zj[p]; z2.y = zj[p];
        acc[0] = __builtin_elementwise_fma(z2, unpk(u[p].x), acc[0]);
        acc[1] = __builtin_elementwise_fma(z2, unpk(u[p].y), acc[1]);
        acc[2] = __builtin_elementwise_fma(z2, unpk(u[p].z), acc[2]);
        acc[3] = __builtin_elementwise_fma(z2, unpk(u[p].w), acc[3]);
    }
}

// Fallback for deg>64 chunks: 16-edge granule, 2 loads in flight.
__device__ __forceinline__ void oct_gather(
    const uint4* __restrict__ fts4, const int2* __restrict__ st,
    int cnt, int sub, int hc, v2f* acc)
{
    const int ngrp = (cnt + 15) >> 4;
    for (int gg = 0; gg < ngrp; ++gg) {
        #pragma unroll
        for (int k = 0; k < 2; ++k) {
            const int2 cz = st[(gg * 2 + k) * 8 + sub];
            const uint4 u = fts4[cz.x + hc];
            const float zjs = __int_as_float(cz.y);
            v2f z2; z2.x = zjs; z2.y = zjs;
            acc[0] = __builtin_elementwise_fma(z2, unpk(u.x), acc[0]);
            acc[1] = __builtin_elementwise_fma(z2, unpk(u.y), acc[1]);
            acc[2] = __builtin_elementwise_fma(z2, unpk(u.z), acc[2]);
            acc[3] = __builtin_elementwise_fma(z2, unpk(u.w), acc[3]);
        }
    }
}

// K3 v4: one wave per destination row (R1-proven regime: short waves, high
// occupancy). Chain is now rptr -> {ecol,zE} streams -> gathers -> consume:
// 3 round trips, ZERO dependent math between gather issue and consume (z is
// precomputed by kz_edge). Unnormalized softmax (algebraically identical).
__global__ __launch_bounds__(256) void k3_attn(
    const int* __restrict__ ecol, const float* __restrict__ zE,
    const int* __restrict__ rptr, const uint4* __restrict__ fts4,
    float* __restrict__ out, int n)
{
    __shared__ int2  stage[4][64];
    __shared__ float red[4][8][64];
    const int lane = threadIdx.x & 63;
    const int wv = threadIdx.x >> 6;
    const int r = blockIdx.x * 4 + wv;
    if (r >= n) return;
    const int start = rptr[r], end = rptr[r + 1], deg = end - start;
    const int sub = lane >> 3;   // which edge of the oct
    const int hc  = lane & 7;    // which 16B chunk of the row
    int2* st = stage[wv];

    v2f acc[4];
    #pragma unroll
    for (int i = 0; i < 4; ++i) { acc[i].x = 0.f; acc[i].y = 0.f; }
    float s = 0.f;

    if (deg <= 64) {
        const int e = start + lane;
        int c = 0; float z = 0.f;
        if (e < end) { c = ecol[e]; z = zE[e]; }
        st[lane] = make_int2(c * 8, __float_as_int(z));
        const int ngrp = (deg + 15) >> 4;   // 0..4, wave-uniform
        switch (ngrp) {
            case 1: gather_batch<1>(fts4, st, sub, hc, acc); break;
            case 2: gather_batch<2>(fts4, st, sub, hc, acc); break;
            case 3: gather_batch<3>(fts4, st, sub, hc, acc); break;
            case 4: gather_batch<4>(fts4, st, sub, hc, acc); break;
            default: break;   // deg==0: acc=0, s=0 -> out=elu(0)=0, matches ref
        }
        s = wave_sum(z);   // DS swizzles overlap outstanding gather loads
    } else {
        for (int base = start; base < end; base += 64) {
            const int e = base + lane;
            int c = 0; float z = 0.f;
            if (e < end) { c = ecol[e]; z = zE[e]; }
            s += z;
            st[lane] = make_int2(c * 8, __float_as_int(z));
            oct_gather(fts4, st, min(64, end - base), sub, hc, acc);
        }
        s = wave_sum(s);
    }

    // epilogue: LDS transpose, 8-way sum per feature, ELU, coalesced store.
    float* rd = &red[wv][0][0];
    *(v4f*)(rd + sub * 64 + hc * 8)     = (v4f){acc[0].x, acc[0].y, acc[1].x, acc[1].y};
    *(v4f*)(rd + sub * 64 + hc * 8 + 4) = (v4f){acc[2].x, acc[2].y, acc[3].x, acc[3].y};
    const float inv = (deg > 0) ? __builtin_amdgcn_rcpf(s) : 0.f;
    float t = 0.f;
    #pragma unroll
    for (int i = 0; i < 8; ++i) t += rd[i * 64 + lane];
    float v = t * inv;
    v = (v > 0.f) ? v : (__expf(v) - 1.f);
    out[(size_t)r * HIDD + lane] = v;
}

extern "C" void kernel_launch(void* const* d_in, const int* in_sizes, int n_in,
                              void* d_out, int out_size, void* d_ws, size_t ws_size,
                              hipStream_t stream)
{
    const float* seq   = (const float*)d_in[0];
    const int*   erow  = (const int*)  d_in[1];
    const int*   ecol  = (const int*)  d_in[2];
    const float* evals = (const float*)d_in[3];
    const float* W     = (const float*)d_in[4];
    const float* a1    = (const float*)d_in[5];
    const float* b1    = (const float*)d_in[6];
    const float* a2    = (const float*)d_in[7];
    const float* b2    = (const float*)d_in[8];
    // d_in[9] = bias_zero (zeros) — additive no-op, skipped.

    const int N = in_sizes[0] / F_INN;
    const int E = in_sizes[1];

    // workspace: fts16 | f1 | f2 | rptr | zE | w1 | w2 | whF | wlF  (~27 MB)
    char* p = (char*)d_ws;
    unsigned short* fts16 = (unsigned short*)p; p += (size_t)N * HIDD * 2;
    float* f1 = (float*)p; p += (size_t)N * 4;
    float* f2 = (float*)p; p += (size_t)N * 4;
    int* rptr = (int*)p;   p += (size_t)(N + 1) * 4;
    float* zE = (float*)p; p += (size_t)E * 4;
    p = (char*)(((uintptr_t)p + 15) & ~(uintptr_t)15);
    float* w1 = (float*)p; p += 128 * 4;
    float* w2 = (float*)p; p += 128 * 4;
    unsigned short* whF = (unsigned short*)p; p += 8192 * 2;
    unsigned short* wlF = (unsigned short*)p;

    float* out = (float*)d_out;

    k0_prep<<<33, 256, 0, stream>>>(W, a1, a2, w1, w2, whF, wlF);

    const int waves1  = (N + 15) / 16;
    const int blocks1 = (waves1 + 3) / 4;
    k1_feat<<<blocks1, 256, 0, stream>>>(seq, whF, wlF, w1, w2, b1, b2,
                                         fts16, f1, f2, N);

    const int eblocks = (E + 255) / 256;
    kz_edge<<<eblocks, 256, 0, stream>>>(erow, ecol, evals, f1, f2,
                                         zE, rptr, N, E);

    const int blocks3 = (N + 3) / 4;
    k3_attn<<<blocks3, 256, 0, stream>>>(ecol, zE, rptr,
                                         (const uint4*)fts16, out, N);
}